// Round 2
// baseline (685.953 us; speedup 1.0000x reference)
//
#include <hip/hip_runtime.h>

#define SEQ 2048
#define HID 1024
#define NHEAD 16
#define HD 64
#define QKVPD 7168
#define VPD 5120
#define NEGV -1e10f

typedef __bf16 bf16;
typedef __attribute__((ext_vector_type(4))) __bf16 bf16x4;
typedef __attribute__((ext_vector_type(8))) __bf16 bf16x8;
typedef __attribute__((ext_vector_type(4))) float f32x4;

#define MFMA16(a, b, c) __builtin_amdgcn_mfma_f32_16x16x32_bf16((a), (b), (c), 0, 0, 0)

#define GLOAD_LDS16(g, l) __builtin_amdgcn_global_load_lds( \
    (const __attribute__((address_space(1))) void*)(g),     \
    (__attribute__((address_space(3))) void*)(l), 16, 0, 0)

// ---------------- block-wide (256 thr) sum+sumsq reduction ----------------
__device__ __forceinline__ void reduce2(float& s, float& ss) {
#pragma unroll
  for (int mk = 32; mk >= 1; mk >>= 1) {
    s  += __shfl_xor(s, mk);
    ss += __shfl_xor(ss, mk);
  }
  __shared__ float rtmp[8];
  const int w = threadIdx.x >> 6;
  if ((threadIdx.x & 63) == 0) { rtmp[2 * w] = s; rtmp[2 * w + 1] = ss; }
  __syncthreads();
  s  = rtmp[0] + rtmp[2] + rtmp[4] + rtmp[6];
  ss = rtmp[1] + rtmp[3] + rtmp[5] + rtmp[7];
}

// ---------------- fp32 -> bf16 weight conversion ----------------
__global__ __launch_bounds__(256) void cvt_f32_bf16(const float* __restrict__ in,
                                                    bf16* __restrict__ out, int n4) {
  int i = blockIdx.x * 256 + threadIdx.x;
  if (i >= n4) return;
  float4 v = ((const float4*)in)[i];
  bf16x4 o = {(bf16)v.x, (bf16)v.y, (bf16)v.z, (bf16)v.w};
  ((bf16x4*)out)[i] = o;
}

// ---------------- input LN + token-shift scatter ----------------
// writes h[t][c] for c>=256 from ln(x[t]); h[t+1][c] for c<256; zeros h[0][0:256]
__global__ __launch_bounds__(256) void ln_in_shift(const float* __restrict__ x,
                                                   const float* __restrict__ g,
                                                   const float* __restrict__ b,
                                                   bf16* __restrict__ h) {
  const int t = blockIdx.x, tid = threadIdx.x;
  float4 v = ((const float4*)(x + (size_t)t * HID))[tid];
  float s = v.x + v.y + v.z + v.w;
  float ss = v.x * v.x + v.y * v.y + v.z * v.z + v.w * v.w;
  reduce2(s, ss);
  float mean = s * (1.f / HID);
  float var = ss * (1.f / HID) - mean * mean;
  float rstd = rsqrtf(var + 1e-5f);
  int c0 = tid * 4;
  float4 gv = ((const float4*)g)[tid];
  float4 bv = ((const float4*)b)[tid];
  bf16x4 o;
  o[0] = (bf16)((v.x - mean) * rstd * gv.x + bv.x);
  o[1] = (bf16)((v.y - mean) * rstd * gv.y + bv.y);
  o[2] = (bf16)((v.z - mean) * rstd * gv.z + bv.z);
  o[3] = (bf16)((v.w - mean) * rstd * gv.w + bv.w);
  if (c0 >= 256) {
    *(bf16x4*)(h + (size_t)t * HID + c0) = o;
  } else {
    if (t + 1 < SEQ) *(bf16x4*)(h + (size_t)(t + 1) * HID + c0) = o;
    if (t == 0) {
      bf16x4 z = {(bf16)0.f, (bf16)0.f, (bf16)0.f, (bf16)0.f};
      *(bf16x4*)(h + c0) = z;
    }
  }
}

// ---------------- q / k LN (bf16 in, bf16 out) ----------------
__global__ __launch_bounds__(256) void ln_qk(const bf16* __restrict__ qkvp,
                                             const float* __restrict__ gq, const float* __restrict__ bq,
                                             const float* __restrict__ gk, const float* __restrict__ bk,
                                             bf16* __restrict__ qo, bf16* __restrict__ ko) {
  const int t = blockIdx.x, z = blockIdx.y, tid = threadIdx.x;
  const bf16* in = qkvp + (size_t)t * QKVPD + z * HID;
  bf16* out = (z ? ko : qo) + (size_t)t * HID;
  const float* g = z ? gk : gq;
  const float* bb = z ? bk : bq;
  int c0 = tid * 4;
  bf16x4 iv = *(const bf16x4*)(in + c0);
  float f0 = (float)iv[0], f1 = (float)iv[1], f2 = (float)iv[2], f3 = (float)iv[3];
  float s = f0 + f1 + f2 + f3;
  float ss = f0 * f0 + f1 * f1 + f2 * f2 + f3 * f3;
  reduce2(s, ss);
  float mean = s * (1.f / HID);
  float var = ss * (1.f / HID) - mean * mean;
  float rstd = rsqrtf(var + 1e-5f);
  float4 gv = ((const float4*)g)[tid];
  float4 bv = ((const float4*)bb)[tid];
  bf16x4 o;
  o[0] = (bf16)((f0 - mean) * rstd * gv.x + bv.x);
  o[1] = (bf16)((f1 - mean) * rstd * gv.y + bv.y);
  o[2] = (bf16)((f2 - mean) * rstd * gv.z + bv.z);
  o[3] = (bf16)((f3 - mean) * rstd * gv.w + bv.w);
  *(bf16x4*)(out + c0) = o;
}

// ---------------- mid LN (4096) + relu -> op[:, 1024:5120] ----------------
__global__ __launch_bounds__(256) void ln_mid(const bf16* __restrict__ qkvp,
                                              const float* __restrict__ g,
                                              const float* __restrict__ b,
                                              bf16* __restrict__ op) {
  const int t = blockIdx.x, tid = threadIdx.x;
  const bf16* in = qkvp + (size_t)t * QKVPD + 3 * HID;
  int c0 = tid * 16;
  bf16x8 a = *(const bf16x8*)(in + c0);
  bf16x8 a2 = *(const bf16x8*)(in + c0 + 8);
  float fv[16];
#pragma unroll
  for (int e = 0; e < 8; ++e) { fv[e] = (float)a[e]; fv[8 + e] = (float)a2[e]; }
  float s = 0.f, ss = 0.f;
#pragma unroll
  for (int e = 0; e < 16; ++e) { s += fv[e]; ss += fv[e] * fv[e]; }
  reduce2(s, ss);
  const float D = 4.f * HID;
  float mean = s / D;
  float var = ss / D - mean * mean;
  float rstd = rsqrtf(var + 1e-5f);
  bf16x8 o1, o2;
#pragma unroll
  for (int q = 0; q < 4; ++q) {
    float4 gv = ((const float4*)g)[tid * 4 + q];
    float4 bv = ((const float4*)b)[tid * 4 + q];
    float r0 = fmaxf(0.f, (fv[q * 4 + 0] - mean) * rstd * gv.x + bv.x);
    float r1 = fmaxf(0.f, (fv[q * 4 + 1] - mean) * rstd * gv.y + bv.y);
    float r2 = fmaxf(0.f, (fv[q * 4 + 2] - mean) * rstd * gv.z + bv.z);
    float r3 = fmaxf(0.f, (fv[q * 4 + 3] - mean) * rstd * gv.w + bv.w);
    if (q < 2) {
      o1[q * 4 + 0] = (bf16)r0; o1[q * 4 + 1] = (bf16)r1;
      o1[q * 4 + 2] = (bf16)r2; o1[q * 4 + 3] = (bf16)r3;
    } else {
      o2[(q - 2) * 4 + 0] = (bf16)r0; o2[(q - 2) * 4 + 1] = (bf16)r1;
      o2[(q - 2) * 4 + 2] = (bf16)r2; o2[(q - 2) * 4 + 3] = (bf16)r3;
    }
  }
  bf16* dst = op + (size_t)t * VPD + HID + c0;
  *(bf16x8*)dst = o1;
  *(bf16x8*)(dst + 8) = o2;
}

// ---------------- out LN (adds out_proj bias first) -> d_out fp32 ----------------
__global__ __launch_bounds__(256) void ln_out(const float* __restrict__ cpre,
                                              const float* __restrict__ bias,
                                              const float* __restrict__ g,
                                              const float* __restrict__ b,
                                              float* __restrict__ outp) {
  const int t = blockIdx.x, tid = threadIdx.x;
  float4 v = ((const float4*)(cpre + (size_t)t * HID))[tid];
  float4 bi = ((const float4*)bias)[tid];
  v.x += bi.x; v.y += bi.y; v.z += bi.z; v.w += bi.w;
  float s = v.x + v.y + v.z + v.w;
  float ss = v.x * v.x + v.y * v.y + v.z * v.z + v.w * v.w;
  reduce2(s, ss);
  float mean = s * (1.f / HID);
  float var = ss * (1.f / HID) - mean * mean;
  float rstd = rsqrtf(var + 1e-5f);
  float4 gv = ((const float4*)g)[tid];
  float4 bv = ((const float4*)b)[tid];
  float4 o;
  o.x = (v.x - mean) * rstd * gv.x + bv.x;
  o.y = (v.y - mean) * rstd * gv.y + bv.y;
  o.z = (v.z - mean) * rstd * gv.z + bv.z;
  o.w = (v.w - mean) * rstd * gv.w + bv.w;
  ((float4*)(outp + (size_t)t * HID))[tid] = o;
}

// ---------------- V transpose: qkvp[:, 2048+h*64+d] -> v_t[h][d][j] ----------------
__global__ __launch_bounds__(256) void vtrans(const bf16* __restrict__ qkvp,
                                              bf16* __restrict__ v_t) {
  const int h = blockIdx.y, j0 = blockIdx.x * 64, tid = threadIdx.x;
  __shared__ bf16 tile[64][72];
  int jr = tid >> 2, dcw = (tid & 3) * 16;
  const bf16* src = qkvp + (size_t)(j0 + jr) * QKVPD + 2 * HID + h * HD + dcw;
  bf16x8 a = *(const bf16x8*)src;
  bf16x8 a2 = *(const bf16x8*)(src + 8);
#pragma unroll
  for (int e = 0; e < 8; ++e) { tile[jr][dcw + e] = a[e]; tile[jr][dcw + 8 + e] = a2[e]; }
  __syncthreads();
  int d = tid >> 2, jc = (tid & 3) * 16;
  bf16x8 o1, o2;
#pragma unroll
  for (int e = 0; e < 8; ++e) { o1[e] = tile[jc + e][d]; o2[e] = tile[jc + 8 + e][d]; }
  bf16* dst = v_t + (size_t)(h * HD + d) * SEQ + j0 + jc;
  *(bf16x8*)dst = o1;
  *(bf16x8*)(dst + 8) = o2;
}

// ---------------- GEMM: C[M][N] = A[M][K] * B[N][K]^T  (m97 structure) ----------------
template <int OUT_BF16>
__global__ __launch_bounds__(256) void gemm_bt(const bf16* __restrict__ A,
                                               const bf16* __restrict__ B,
                                               void* __restrict__ Cout,
                                               int M, int N, int K) {
  __shared__ bf16 As[128 * 32], Bs[128 * 32];
  const int tid = threadIdx.x;
  const int l = tid & 63, w = tid >> 6;
  const int wr = w >> 1, wc = w & 1;
  const int lr = l & 15, lg = l >> 4;
  const int m0 = blockIdx.y * 128, n0 = blockIdx.x * 128;

  f32x4 acc[4][4];
#pragma unroll
  for (int i = 0; i < 4; ++i)
#pragma unroll
    for (int j = 0; j < 4; ++j) acc[i][j] = (f32x4){0.f, 0.f, 0.f, 0.f};

  for (int k0 = 0; k0 < K; k0 += 32) {
#pragma unroll
    for (int p = 0; p < 2; ++p) {
      int idx = p * 256 + tid;
      int row = idx >> 2, cc = (idx & 3) * 8;
      GLOAD_LDS16(A + (size_t)(m0 + row) * K + k0 + cc, As + idx * 8);
      GLOAD_LDS16(B + (size_t)(n0 + row) * K + k0 + cc, Bs + idx * 8);
    }
    __syncthreads();
    bf16x8 af[4], bfr[4];
#pragma unroll
    for (int i = 0; i < 4; ++i) {
      af[i]  = *(const bf16x8*)(As + (wr * 64 + i * 16 + lr) * 32 + lg * 8);
      bfr[i] = *(const bf16x8*)(Bs + (wc * 64 + i * 16 + lr) * 32 + lg * 8);
    }
#pragma unroll
    for (int i = 0; i < 4; ++i)
#pragma unroll
      for (int j = 0; j < 4; ++j) acc[i][j] = MFMA16(af[i], bfr[j], acc[i][j]);
    __syncthreads();
  }

#pragma unroll
  for (int i = 0; i < 4; ++i)
#pragma unroll
    for (int j = 0; j < 4; ++j)
#pragma unroll
      for (int r = 0; r < 4; ++r) {
        int rr = m0 + wr * 64 + i * 16 + lg * 4 + r;
        int cc = n0 + wc * 64 + j * 16 + lr;
        if (OUT_BF16)
          ((bf16*)Cout)[(size_t)rr * N + cc] = (bf16)acc[i][j][r];
        else
          ((float*)Cout)[(size_t)rr * N + cc] = acc[i][j][r];
      }
}

// ---------------- fused attention ----------------
// grid = SEQ/16 blocks, 1024 threads (16 waves = 16 heads), i-tile = 16 rows.
// QK^T for ALL j (residual needs unmasked logits); softmax+PV only for causal tiles.
__global__ __launch_bounds__(1024) void attn_kernel(const bf16* __restrict__ q_ln,
                                                    const bf16* __restrict__ k_ln,
                                                    const bf16* __restrict__ v_t,
                                                    const float* __restrict__ acc_lg,
                                                    bf16* __restrict__ o_out,
                                                    float* __restrict__ resid) {
  const int i0 = blockIdx.x * 16;
  const int tid = threadIdx.x;
  const int w = tid >> 6;           // head
  const int l = tid & 63;
  const int lr = l & 15, lg = l >> 4;
  const int hoff = w * HD;

  __shared__ float red[512 * 17];         // [loc 0..511][head], pad 17 -> conflict-free
  __shared__ bf16 pbuf[NHEAD][16 * 56];   // P round-trip, row stride 56 (16B aligned)

  const float slope = exp2f(-0.5f * (float)(w + 1));  // alibi slope, heads=16

  bf16x8 qf[2];
#pragma unroll
  for (int kc = 0; kc < 2; ++kc)
    qf[kc] = *(const bf16x8*)(q_ln + (size_t)(i0 + lr) * HID + hoff + kc * 32 + lg * 8);

  f32x4 oacc[4] = {{0.f, 0.f, 0.f, 0.f}, {0.f, 0.f, 0.f, 0.f},
                   {0.f, 0.f, 0.f, 0.f}, {0.f, 0.f, 0.f, 0.f}};
  float mrow[4] = {-3e38f, -3e38f, -3e38f, -3e38f};
  float lsum[4] = {0.f, 0.f, 0.f, 0.f};

  for (int j0 = 0; j0 < SEQ; j0 += 32) {
    const bool active = (j0 <= i0 + 15);
    // ---- QK^T (always; residual needs full logits) ----
    f32x4 s[2];
#pragma unroll
    for (int jh = 0; jh < 2; ++jh) {
      f32x4 a = {0.f, 0.f, 0.f, 0.f};
#pragma unroll
      for (int kc = 0; kc < 2; ++kc) {
        bf16x8 kf = *(const bf16x8*)(k_ln + (size_t)(j0 + jh * 16 + lr) * HID +
                                     hoff + kc * 32 + lg * 8);
        a = MFMA16(qf[kc], kf, a);
      }
      s[jh] = a * 0.125f;
    }
    // stage raw logits for head-mean
#pragma unroll
    for (int jh = 0; jh < 2; ++jh)
#pragma unroll
      for (int r = 0; r < 4; ++r)
        red[((lg * 4 + r) * 32 + jh * 16 + lr) * 17 + w] = s[jh][r];

    if (active) {
      float f[2][4];
#pragma unroll
      for (int jh = 0; jh < 2; ++jh)
#pragma unroll
        for (int r = 0; r < 4; ++r) {
          int i = i0 + lg * 4 + r;
          int j = j0 + jh * 16 + lr;
          f[jh][r] = s[jh][r] + acc_lg[(size_t)i * SEQ + j] + slope * (float)j +
                     ((j <= i) ? 0.f : NEGV);
        }
#pragma unroll
      for (int r = 0; r < 4; ++r) {
        float vm = fmaxf(f[0][r], f[1][r]);
#pragma unroll
        for (int mk = 1; mk < 16; mk <<= 1) vm = fmaxf(vm, __shfl_xor(vm, mk));
        float mnew = fmaxf(mrow[r], vm);
        float scale = __expf(mrow[r] - mnew);
        float p0 = __expf(f[0][r] - mnew);
        float p1 = __expf(f[1][r] - mnew);
        float ps = p0 + p1;
#pragma unroll
        for (int mk = 1; mk < 16; mk <<= 1) ps += __shfl_xor(ps, mk);
        lsum[r] = lsum[r] * scale + ps;
        mrow[r] = mnew;
#pragma unroll
        for (int dc = 0; dc < 4; ++dc) oacc[dc][r] *= scale;
        pbuf[w][(lg * 4 + r) * 56 + lr] = (bf16)p0;
        pbuf[w][(lg * 4 + r) * 56 + 16 + lr] = (bf16)p1;
      }
    }
    __syncthreads();
    // head-mean residual write (once per element, no atomics)
    if (tid < 512) {
      float sum = 0.f;
#pragma unroll
      for (int hh = 0; hh < 16; ++hh) sum += red[tid * 17 + hh];
      resid[(size_t)(i0 + (tid >> 5)) * SEQ + j0 + (tid & 31)] = sum * 0.0625f;
    }
    if (active) {
      bf16x8 pa = *(const bf16x8*)(&pbuf[w][lr * 56 + lg * 8]);
#pragma unroll
      for (int dc = 0; dc < 4; ++dc) {
        bf16x8 vb = *(const bf16x8*)(v_t + (size_t)(hoff + dc * 16 + lr) * SEQ +
                                     j0 + lg * 8);
        oacc[dc] = MFMA16(pa, vb, oacc[dc]);
      }
    }
    __syncthreads();
  }

#pragma unroll
  for (int dc = 0; dc < 4; ++dc)
#pragma unroll
    for (int r = 0; r < 4; ++r) {
      float o = oacc[dc][r] / lsum[r];
      o_out[(size_t)(i0 + lg * 4 + r) * VPD + hoff + dc * 16 + lr] = (bf16)o;
    }
}

// ---------------- launch ----------------
extern "C" void kernel_launch(void* const* d_in, const int* in_sizes, int n_in,
                              void* d_out, int out_size, void* d_ws, size_t ws_size,
                              hipStream_t stream) {
  const float* x      = (const float*)d_in[0];
  const float* acc_lg = (const float*)d_in[1];
  const float* w_in   = (const float*)d_in[2];
  const float* w_out  = (const float*)d_in[3];
  const float* b_out  = (const float*)d_in[4];
  const float* g_in   = (const float*)d_in[5];
  const float* bi_in  = (const float*)d_in[6];
  const float* g_q    = (const float*)d_in[7];
  const float* bi_q   = (const float*)d_in[8];
  const float* g_k    = (const float*)d_in[9];
  const float* bi_k   = (const float*)d_in[10];
  const float* g_mid  = (const float*)d_in[11];
  const float* bi_mid = (const float*)d_in[12];
  const float* g_out  = (const float*)d_in[13];
  const float* bi_o   = (const float*)d_in[14];

  char* ws = (char*)d_ws;
  bf16* h_shift = (bf16*)(ws + 0);            //  4 MB  [2048][1024]
  bf16* wA      = (bf16*)(ws + 4194304);      // 14 MB  [7168][1024]
  bf16* wO      = (bf16*)(ws + 18874368);     // 10 MB  [1024][5120]
  bf16* qkvp    = (bf16*)(ws + 29360128);     // 29 MB  [2048][7168]
  bf16* q_ln    = (bf16*)(ws + 58720256);     //  4 MB
  bf16* k_ln    = (bf16*)(ws + 62914560);     //  4 MB
  bf16* v_t     = (bf16*)(ws + 67108864);     //  4 MB  [16][64][2048]
  bf16* op      = (bf16*)(ws + 71303168);     // 21 MB  [2048][5120] (o | p)
  // out_pre aliases the qkvp region: all qkvp consumers (ln_qk, ln_mid, vtrans)
  // run before gemm2 writes out_pre. Keeps ws peak at 88 MB.
  float* out_pre= (float*)qkvp;               //  8 MB  [2048][1024] fp32

  float* outp  = (float*)d_out;
  float* resid = outp + (size_t)SEQ * HID;

  cvt_f32_bf16<<<7168, 256, 0, stream>>>(w_in, wA, QKVPD * HID / 4);
  cvt_f32_bf16<<<5120, 256, 0, stream>>>(w_out, wO, HID * VPD / 4);
  ln_in_shift<<<SEQ, 256, 0, stream>>>(x, g_in, bi_in, h_shift);
  gemm_bt<1><<<dim3(QKVPD / 128, SEQ / 128), 256, 0, stream>>>(h_shift, wA, qkvp,
                                                               SEQ, QKVPD, HID);
  ln_qk<<<dim3(SEQ, 2), 256, 0, stream>>>(qkvp, g_q, bi_q, g_k, bi_k, q_ln, k_ln);
  ln_mid<<<SEQ, 256, 0, stream>>>(qkvp, g_mid, bi_mid, op);
  vtrans<<<dim3(SEQ / 64, NHEAD), 256, 0, stream>>>(qkvp, v_t);
  attn_kernel<<<SEQ / 16, 1024, 0, stream>>>(q_ln, k_ln, v_t, acc_lg, op, resid);
  gemm_bt<0><<<dim3(HID / 128, SEQ / 128), 256, 0, stream>>>(op, wO, out_pre,
                                                             SEQ, HID, VPD);
  ln_out<<<SEQ, 256, 0, stream>>>(out_pre, b_out, g_out, bi_o, outp);
}

// Round 7
// 396.606 us; speedup vs baseline: 1.7296x; 1.7296x over previous
//
#include <hip/hip_runtime.h>

#define SEQ 2048
#define HID 1024
#define NHEAD 16
#define HD 64
#define QKVPD 7168
#define VPD 5120
#define NEGV -1e10f

typedef __bf16 bf16;
typedef __attribute__((ext_vector_type(4))) __bf16 bf16x4;
typedef __attribute__((ext_vector_type(8))) __bf16 bf16x8;
typedef __attribute__((ext_vector_type(4))) float f32x4;

#define MFMA16(a, b, c) __builtin_amdgcn_mfma_f32_16x16x32_bf16((a), (b), (c), 0, 0, 0)

#define GLOAD_LDS16(g, l) __builtin_amdgcn_global_load_lds( \
    (const __attribute__((address_space(1))) void*)(g),     \
    (__attribute__((address_space(3))) void*)(l), 16, 0, 0)

// ---------------- block-wide (256 thr) sum+sumsq reduction ----------------
__device__ __forceinline__ void reduce2(float& s, float& ss) {
#pragma unroll
  for (int mk = 32; mk >= 1; mk >>= 1) {
    s  += __shfl_xor(s, mk);
    ss += __shfl_xor(ss, mk);
  }
  __shared__ float rtmp[8];
  const int w = threadIdx.x >> 6;
  if ((threadIdx.x & 63) == 0) { rtmp[2 * w] = s; rtmp[2 * w + 1] = ss; }
  __syncthreads();
  s  = rtmp[0] + rtmp[2] + rtmp[4] + rtmp[6];
  ss = rtmp[1] + rtmp[3] + rtmp[5] + rtmp[7];
}

// ---------------- fp32 -> bf16 weight conversion ----------------
__global__ __launch_bounds__(256) void cvt_f32_bf16(const float* __restrict__ in,
                                                    bf16* __restrict__ out, int n4) {
  int i = blockIdx.x * 256 + threadIdx.x;
  if (i >= n4) return;
  float4 v = ((const float4*)in)[i];
  bf16x4 o = {(bf16)v.x, (bf16)v.y, (bf16)v.z, (bf16)v.w};
  ((bf16x4*)out)[i] = o;
}

// ---------------- input LN + token-shift scatter ----------------
__global__ __launch_bounds__(256) void ln_in_shift(const float* __restrict__ x,
                                                   const float* __restrict__ g,
                                                   const float* __restrict__ b,
                                                   bf16* __restrict__ h) {
  const int t = blockIdx.x, tid = threadIdx.x;
  float4 v = ((const float4*)(x + (size_t)t * HID))[tid];
  float s = v.x + v.y + v.z + v.w;
  float ss = v.x * v.x + v.y * v.y + v.z * v.z + v.w * v.w;
  reduce2(s, ss);
  float mean = s * (1.f / HID);
  float var = ss * (1.f / HID) - mean * mean;
  float rstd = rsqrtf(var + 1e-5f);
  int c0 = tid * 4;
  float4 gv = ((const float4*)g)[tid];
  float4 bv = ((const float4*)b)[tid];
  bf16x4 o;
  o[0] = (bf16)((v.x - mean) * rstd * gv.x + bv.x);
  o[1] = (bf16)((v.y - mean) * rstd * gv.y + bv.y);
  o[2] = (bf16)((v.z - mean) * rstd * gv.z + bv.z);
  o[3] = (bf16)((v.w - mean) * rstd * gv.w + bv.w);
  if (c0 >= 256) {
    *(bf16x4*)(h + (size_t)t * HID + c0) = o;
  } else {
    if (t + 1 < SEQ) *(bf16x4*)(h + (size_t)(t + 1) * HID + c0) = o;
    if (t == 0) {
      bf16x4 z = {(bf16)0.f, (bf16)0.f, (bf16)0.f, (bf16)0.f};
      *(bf16x4*)(h + c0) = z;
    }
  }
}

// ---------------- q / k LN (bf16 in, bf16 out) ----------------
__global__ __launch_bounds__(256) void ln_qk(const bf16* __restrict__ qkvp,
                                             const float* __restrict__ gq, const float* __restrict__ bq,
                                             const float* __restrict__ gk, const float* __restrict__ bk,
                                             bf16* __restrict__ qo, bf16* __restrict__ ko) {
  const int t = blockIdx.x, z = blockIdx.y, tid = threadIdx.x;
  const bf16* in = qkvp + (size_t)t * QKVPD + z * HID;
  bf16* out = (z ? ko : qo) + (size_t)t * HID;
  const float* g = z ? gk : gq;
  const float* bb = z ? bk : bq;
  int c0 = tid * 4;
  bf16x4 iv = *(const bf16x4*)(in + c0);
  float f0 = (float)iv[0], f1 = (float)iv[1], f2 = (float)iv[2], f3 = (float)iv[3];
  float s = f0 + f1 + f2 + f3;
  float ss = f0 * f0 + f1 * f1 + f2 * f2 + f3 * f3;
  reduce2(s, ss);
  float mean = s * (1.f / HID);
  float var = ss * (1.f / HID) - mean * mean;
  float rstd = rsqrtf(var + 1e-5f);
  float4 gv = ((const float4*)g)[tid];
  float4 bv = ((const float4*)bb)[tid];
  bf16x4 o;
  o[0] = (bf16)((f0 - mean) * rstd * gv.x + bv.x);
  o[1] = (bf16)((f1 - mean) * rstd * gv.y + bv.y);
  o[2] = (bf16)((f2 - mean) * rstd * gv.z + bv.z);
  o[3] = (bf16)((f3 - mean) * rstd * gv.w + bv.w);
  *(bf16x4*)(out + c0) = o;
}

// ---------------- mid LN (4096) + relu -> op[:, 1024:5120] ----------------
__global__ __launch_bounds__(256) void ln_mid(const bf16* __restrict__ qkvp,
                                              const float* __restrict__ g,
                                              const float* __restrict__ b,
                                              bf16* __restrict__ op) {
  const int t = blockIdx.x, tid = threadIdx.x;
  const bf16* in = qkvp + (size_t)t * QKVPD + 3 * HID;
  int c0 = tid * 16;
  bf16x8 a = *(const bf16x8*)(in + c0);
  bf16x8 a2 = *(const bf16x8*)(in + c0 + 8);
  float fv[16];
#pragma unroll
  for (int e = 0; e < 8; ++e) { fv[e] = (float)a[e]; fv[8 + e] = (float)a2[e]; }
  float s = 0.f, ss = 0.f;
#pragma unroll
  for (int e = 0; e < 16; ++e) { s += fv[e]; ss += fv[e] * fv[e]; }
  reduce2(s, ss);
  const float D = 4.f * HID;
  float mean = s / D;
  float var = ss / D - mean * mean;
  float rstd = rsqrtf(var + 1e-5f);
  bf16x8 o1, o2;
#pragma unroll
  for (int q = 0; q < 4; ++q) {
    float4 gv = ((const float4*)g)[tid * 4 + q];
    float4 bv = ((const float4*)b)[tid * 4 + q];
    float r0 = fmaxf(0.f, (fv[q * 4 + 0] - mean) * rstd * gv.x + bv.x);
    float r1 = fmaxf(0.f, (fv[q * 4 + 1] - mean) * rstd * gv.y + bv.y);
    float r2 = fmaxf(0.f, (fv[q * 4 + 2] - mean) * rstd * gv.z + bv.z);
    float r3 = fmaxf(0.f, (fv[q * 4 + 3] - mean) * rstd * gv.w + bv.w);
    if (q < 2) {
      o1[q * 4 + 0] = (bf16)r0; o1[q * 4 + 1] = (bf16)r1;
      o1[q * 4 + 2] = (bf16)r2; o1[q * 4 + 3] = (bf16)r3;
    } else {
      o2[(q - 2) * 4 + 0] = (bf16)r0; o2[(q - 2) * 4 + 1] = (bf16)r1;
      o2[(q - 2) * 4 + 2] = (bf16)r2; o2[(q - 2) * 4 + 3] = (bf16)r3;
    }
  }
  bf16* dst = op + (size_t)t * VPD + HID + c0;
  *(bf16x8*)dst = o1;
  *(bf16x8*)(dst + 8) = o2;
}

// ---------------- out LN: sum split-K partials + bias, then LN -> fp32 ----------------
__global__ __launch_bounds__(256) void ln_out(const float* __restrict__ cp0,
                                              const float* __restrict__ cp1,
                                              const float* __restrict__ bias,
                                              const float* __restrict__ g,
                                              const float* __restrict__ b,
                                              float* __restrict__ outp) {
  const int t = blockIdx.x, tid = threadIdx.x;
  float4 v  = ((const float4*)(cp0 + (size_t)t * HID))[tid];
  float4 v1 = ((const float4*)(cp1 + (size_t)t * HID))[tid];
  float4 bi = ((const float4*)bias)[tid];
  v.x += v1.x + bi.x; v.y += v1.y + bi.y; v.z += v1.z + bi.z; v.w += v1.w + bi.w;
  float s = v.x + v.y + v.z + v.w;
  float ss = v.x * v.x + v.y * v.y + v.z * v.z + v.w * v.w;
  reduce2(s, ss);
  float mean = s * (1.f / HID);
  float var = ss * (1.f / HID) - mean * mean;
  float rstd = rsqrtf(var + 1e-5f);
  float4 gv = ((const float4*)g)[tid];
  float4 bv = ((const float4*)b)[tid];
  float4 o;
  o.x = (v.x - mean) * rstd * gv.x + bv.x;
  o.y = (v.y - mean) * rstd * gv.y + bv.y;
  o.z = (v.z - mean) * rstd * gv.z + bv.z;
  o.w = (v.w - mean) * rstd * gv.w + bv.w;
  ((float4*)(outp + (size_t)t * HID))[tid] = o;
}

// ---------------- V transpose: qkvp[:, 2048+h*64+d] -> v_t[h][d][j] ----------------
__global__ __launch_bounds__(256) void vtrans(const bf16* __restrict__ qkvp,
                                              bf16* __restrict__ v_t) {
  const int h = blockIdx.y, j0 = blockIdx.x * 64, tid = threadIdx.x;
  __shared__ bf16 tile[64][72];
  int jr = tid >> 2, dcw = (tid & 3) * 16;
  const bf16* src = qkvp + (size_t)(j0 + jr) * QKVPD + 2 * HID + h * HD + dcw;
  bf16x8 a = *(const bf16x8*)src;
  bf16x8 a2 = *(const bf16x8*)(src + 8);
#pragma unroll
  for (int e = 0; e < 8; ++e) { tile[jr][dcw + e] = a[e]; tile[jr][dcw + 8 + e] = a2[e]; }
  __syncthreads();
  int d = tid >> 2, jc = (tid & 3) * 16;
  bf16x8 o1, o2;
#pragma unroll
  for (int e = 0; e < 8; ++e) { o1[e] = tile[jc + e][d]; o2[e] = tile[jc + 8 + e][d]; }
  bf16* dst = v_t + (size_t)(h * HD + d) * SEQ + j0 + jc;
  *(bf16x8*)dst = o1;
  *(bf16x8*)(dst + 8) = o2;
}

// ---------------- GEMM: C[M][N] = A[M][K]*B[N][K]^T, split-K via blockIdx.z ----
// ld = row stride of A and B; k-range = [z*kLen, (z+1)*kLen); fp32 out offset z*M*N.
template <int OUT_BF16>
__global__ __launch_bounds__(256) void gemm_bt(const bf16* __restrict__ A,
                                               const bf16* __restrict__ B,
                                               void* __restrict__ Cout,
                                               int M, int N, int ld, int kLen,
                                               float scale) {
  __shared__ bf16 As[128 * 32], Bs[128 * 32];
  const int tid = threadIdx.x;
  const int l = tid & 63, w = tid >> 6;
  const int wr = w >> 1, wc = w & 1;
  const int lr = l & 15, lg = l >> 4;
  const int m0 = blockIdx.y * 128, n0 = blockIdx.x * 128;
  const int kBeg = blockIdx.z * kLen, kEnd = kBeg + kLen;

  f32x4 acc[4][4];
#pragma unroll
  for (int i = 0; i < 4; ++i)
#pragma unroll
    for (int j = 0; j < 4; ++j) acc[i][j] = (f32x4){0.f, 0.f, 0.f, 0.f};

  for (int k0 = kBeg; k0 < kEnd; k0 += 32) {
#pragma unroll
    for (int p = 0; p < 2; ++p) {
      int idx = p * 256 + tid;
      int row = idx >> 2, cc = (idx & 3) * 8;
      GLOAD_LDS16(A + (size_t)(m0 + row) * ld + k0 + cc, As + idx * 8);
      GLOAD_LDS16(B + (size_t)(n0 + row) * ld + k0 + cc, Bs + idx * 8);
    }
    __syncthreads();
    bf16x8 af[4], bfr[4];
#pragma unroll
    for (int i = 0; i < 4; ++i) {
      af[i]  = *(const bf16x8*)(As + (wr * 64 + i * 16 + lr) * 32 + lg * 8);
      bfr[i] = *(const bf16x8*)(Bs + (wc * 64 + i * 16 + lr) * 32 + lg * 8);
    }
#pragma unroll
    for (int i = 0; i < 4; ++i)
#pragma unroll
      for (int j = 0; j < 4; ++j) acc[i][j] = MFMA16(af[i], bfr[j], acc[i][j]);
    __syncthreads();
  }

  float* cf = (float*)Cout + (size_t)blockIdx.z * M * N;
#pragma unroll
  for (int i = 0; i < 4; ++i)
#pragma unroll
    for (int j = 0; j < 4; ++j)
#pragma unroll
      for (int r = 0; r < 4; ++r) {
        int rr = m0 + wr * 64 + i * 16 + lg * 4 + r;
        int cc = n0 + wc * 64 + j * 16 + lr;
        if (OUT_BF16)
          ((bf16*)Cout)[(size_t)rr * N + cc] = (bf16)acc[i][j][r];
        else
          cf[(size_t)rr * N + cc] = acc[i][j][r] * scale;
      }
}

// ---------------- causal flash attention ----------------
// grid = (NHEAD, 32); 256 threads = 4 independent waves (no barriers).
// Wave w of block y owns 16 rows: rowblock R in {2y, 2y+1, 126-2y, 127-2y}
// (pairs long+short causal spans -> every block has identical total work).
__global__ __launch_bounds__(256) void attn_flash(const bf16* __restrict__ q_ln,
                                                  const bf16* __restrict__ k_ln,
                                                  const bf16* __restrict__ v_t,
                                                  const float* __restrict__ acc_lg,
                                                  bf16* __restrict__ o_out) {
  const int head = blockIdx.x;
  const int y = blockIdx.y;
  const int tid = threadIdx.x;
  const int w = tid >> 6, l = tid & 63;
  const int lr = l & 15, lg = l >> 4;
  int R;
  if (w == 0) R = 2 * y; else if (w == 1) R = 2 * y + 1;
  else if (w == 2) R = 126 - 2 * y; else R = 127 - 2 * y;
  const int i0 = R * 16;
  const int hoff = head * HD;
  const float slope = exp2f(-0.5f * (float)(head + 1));

  __shared__ bf16 pbuf[4][16 * 40];   // per-wave P tile, stride 40 (16B-aligned rows)
  bf16* pb = pbuf[w];

  bf16x8 qf[2];
#pragma unroll
  for (int kc = 0; kc < 2; ++kc)
    qf[kc] = *(const bf16x8*)(q_ln + (size_t)(i0 + lr) * HID + hoff + kc * 32 + lg * 8);

  f32x4 oacc[4] = {{0.f, 0.f, 0.f, 0.f}, {0.f, 0.f, 0.f, 0.f},
                   {0.f, 0.f, 0.f, 0.f}, {0.f, 0.f, 0.f, 0.f}};
  float mrow[4] = {-3e38f, -3e38f, -3e38f, -3e38f};
  float lsum[4] = {0.f, 0.f, 0.f, 0.f};

  for (int j0 = 0; j0 <= i0 + 15; j0 += 32) {
    // ---- QK^T ----
    f32x4 s[2];
#pragma unroll
    for (int jh = 0; jh < 2; ++jh) {
      f32x4 a = {0.f, 0.f, 0.f, 0.f};
#pragma unroll
      for (int kc = 0; kc < 2; ++kc) {
        bf16x8 kf = *(const bf16x8*)(k_ln + (size_t)(j0 + jh * 16 + lr) * HID +
                                     hoff + kc * 32 + lg * 8);
        a = MFMA16(qf[kc], kf, a);
      }
      s[jh] = a * 0.125f;
    }
    // ---- bias + mask ----
    float f[2][4];
#pragma unroll
    for (int jh = 0; jh < 2; ++jh)
#pragma unroll
      for (int r = 0; r < 4; ++r) {
        int i = i0 + lg * 4 + r;
        int j = j0 + jh * 16 + lr;
        f[jh][r] = s[jh][r] + acc_lg[(size_t)i * SEQ + j] + slope * (float)j +
                   ((j <= i) ? 0.f : NEGV);
      }
    // ---- online softmax (reduce over 16 lr lanes) ----
#pragma unroll
    for (int r = 0; r < 4; ++r) {
      float vm = fmaxf(f[0][r], f[1][r]);
#pragma unroll
      for (int mk = 1; mk < 16; mk <<= 1) vm = fmaxf(vm, __shfl_xor(vm, mk));
      float mnew = fmaxf(mrow[r], vm);
      float scl = __expf(mrow[r] - mnew);
      float p0 = __expf(f[0][r] - mnew);
      float p1 = __expf(f[1][r] - mnew);
      float ps = p0 + p1;
#pragma unroll
      for (int mk = 1; mk < 16; mk <<= 1) ps += __shfl_xor(ps, mk);
      lsum[r] = lsum[r] * scl + ps;
      mrow[r] = mnew;
#pragma unroll
      for (int dc = 0; dc < 4; ++dc) oacc[dc][r] *= scl;
      pb[(lg * 4 + r) * 40 + lr] = (bf16)p0;
      pb[(lg * 4 + r) * 40 + 16 + lr] = (bf16)p1;
    }
    // intra-wave LDS write->read fence (no cross-wave sharing, so no barrier)
    asm volatile("s_waitcnt lgkmcnt(0)" ::: "memory");
    // ---- PV ----
    bf16x8 pa = *(const bf16x8*)(pb + lr * 40 + lg * 8);
#pragma unroll
    for (int dc = 0; dc < 4; ++dc) {
      bf16x8 vb = *(const bf16x8*)(v_t + (size_t)(hoff + dc * 16 + lr) * SEQ +
                                   j0 + lg * 8);
      oacc[dc] = MFMA16(pa, vb, oacc[dc]);
    }
  }

#pragma unroll
  for (int dc = 0; dc < 4; ++dc)
#pragma unroll
    for (int r = 0; r < 4; ++r) {
      float o = oacc[dc][r] / lsum[r];
      o_out[(size_t)(i0 + lg * 4 + r) * VPD + hoff + dc * 16 + lr] = (bf16)o;
    }
}

// ---------------- launch ----------------
extern "C" void kernel_launch(void* const* d_in, const int* in_sizes, int n_in,
                              void* d_out, int out_size, void* d_ws, size_t ws_size,
                              hipStream_t stream) {
  const float* x      = (const float*)d_in[0];
  const float* acc_lg = (const float*)d_in[1];
  const float* w_in   = (const float*)d_in[2];
  const float* w_out  = (const float*)d_in[3];
  const float* b_out  = (const float*)d_in[4];
  const float* g_in   = (const float*)d_in[5];
  const float* bi_in  = (const float*)d_in[6];
  const float* g_q    = (const float*)d_in[7];
  const float* bi_q   = (const float*)d_in[8];
  const float* g_k    = (const float*)d_in[9];
  const float* bi_k   = (const float*)d_in[10];
  const float* g_mid  = (const float*)d_in[11];
  const float* bi_mid = (const float*)d_in[12];
  const float* g_out  = (const float*)d_in[13];
  const float* bi_o   = (const float*)d_in[14];

  char* ws = (char*)d_ws;
  bf16* h_shift = (bf16*)(ws + 0);            //  4 MB  [2048][1024]
  bf16* wA      = (bf16*)(ws + 4194304);      // 14 MB  [7168][1024]
  bf16* wO      = (bf16*)(ws + 18874368);     // 10 MB  [1024][5120]
  bf16* qkvp    = (bf16*)(ws + 29360128);     // 29 MB  [2048][7168]
  bf16* q_ln    = (bf16*)(ws + 58720256);     //  4 MB
  bf16* k_ln    = (bf16*)(ws + 62914560);     //  4 MB
  bf16* v_t     = (bf16*)(ws + 67108864);     //  4 MB  [16][64][2048]
  bf16* op      = (bf16*)(ws + 71303168);     // 21 MB  [2048][5120] (o | p)
  // out_pre (2 split-K partials, 16 MB fp32) aliases qkvp: all qkvp consumers
  // (ln_qk, ln_mid, vtrans) run before gemm2 writes it.
  float* out_pre = (float*)qkvp;

  float* outp  = (float*)d_out;
  float* resid = outp + (size_t)SEQ * HID;

  cvt_f32_bf16<<<7168, 256, 0, stream>>>(w_in, wA, QKVPD * HID / 4);
  cvt_f32_bf16<<<5120, 256, 0, stream>>>(w_out, wO, HID * VPD / 4);
  ln_in_shift<<<SEQ, 256, 0, stream>>>(x, g_in, bi_in, h_shift);
  gemm_bt<1><<<dim3(QKVPD / 128, SEQ / 128), 256, 0, stream>>>(
      h_shift, wA, qkvp, SEQ, QKVPD, HID, HID, 1.f);
  ln_qk<<<dim3(SEQ, 2), 256, 0, stream>>>(qkvp, g_q, bi_q, g_k, bi_k, q_ln, k_ln);
  ln_mid<<<SEQ, 256, 0, stream>>>(qkvp, g_mid, bi_mid, op);
  vtrans<<<dim3(SEQ / 64, NHEAD), 256, 0, stream>>>(qkvp, v_t);
  // logit_residual = (q_ln . k_ln^T) / (8*16)  — heads partition channels
  gemm_bt<0><<<dim3(SEQ / 128, SEQ / 128), 256, 0, stream>>>(
      q_ln, k_ln, resid, SEQ, SEQ, HID, HID, 1.f / 128.f);
  attn_flash<<<dim3(NHEAD, 32), 256, 0, stream>>>(q_ln, k_ln, v_t, acc_lg, op);
  gemm_bt<0><<<dim3(HID / 128, SEQ / 128, 2), 256, 0, stream>>>(
      op, wO, out_pre, SEQ, HID, VPD, VPD / 2, 1.f);
  ln_out<<<SEQ, 256, 0, stream>>>(out_pre, out_pre + (size_t)SEQ * HID,
                                  b_out, g_out, bi_o, outp);
}

// Round 9
// 375.876 us; speedup vs baseline: 1.8249x; 1.0552x over previous
//
#include <hip/hip_runtime.h>

#define SEQ 2048
#define HID 1024
#define NHEAD 16
#define HD 64
#define QKVPD 7168
#define VPD 5120
#define NEGV -1e10f

typedef __bf16 bf16;
typedef __attribute__((ext_vector_type(4))) __bf16 bf16x4;
typedef __attribute__((ext_vector_type(8))) __bf16 bf16x8;
typedef __attribute__((ext_vector_type(4))) float f32x4;

#define MFMA16(a, b, c) __builtin_amdgcn_mfma_f32_16x16x32_bf16((a), (b), (c), 0, 0, 0)

#define GLOAD_LDS16(g, l) __builtin_amdgcn_global_load_lds( \
    (const __attribute__((address_space(1))) void*)(g),     \
    (__attribute__((address_space(3))) void*)(l), 16, 0, 0)

#define L2E 1.44269504f

// ---------------- block-wide (256 thr) sum+sumsq reduction ----------------
__device__ __forceinline__ void reduce2(float& s, float& ss) {
#pragma unroll
  for (int mk = 32; mk >= 1; mk >>= 1) {
    s  += __shfl_xor(s, mk);
    ss += __shfl_xor(ss, mk);
  }
  __shared__ float rtmp[8];
  const int w = threadIdx.x >> 6;
  if ((threadIdx.x & 63) == 0) { rtmp[2 * w] = s; rtmp[2 * w + 1] = ss; }
  __syncthreads();
  s  = rtmp[0] + rtmp[2] + rtmp[4] + rtmp[6];
  ss = rtmp[1] + rtmp[3] + rtmp[5] + rtmp[7];
}

// ---------------- fp32 -> bf16 weight conversion ----------------
__global__ __launch_bounds__(256) void cvt_f32_bf16(const float* __restrict__ in,
                                                    bf16* __restrict__ out, int n4) {
  int i = blockIdx.x * 256 + threadIdx.x;
  if (i >= n4) return;
  float4 v = ((const float4*)in)[i];
  bf16x4 o = {(bf16)v.x, (bf16)v.y, (bf16)v.z, (bf16)v.w};
  ((bf16x4*)out)[i] = o;
}

// ---------------- input LN + token-shift scatter ----------------
__global__ __launch_bounds__(256) void ln_in_shift(const float* __restrict__ x,
                                                   const float* __restrict__ g,
                                                   const float* __restrict__ b,
                                                   bf16* __restrict__ h) {
  const int t = blockIdx.x, tid = threadIdx.x;
  float4 v = ((const float4*)(x + (size_t)t * HID))[tid];
  float s = v.x + v.y + v.z + v.w;
  float ss = v.x * v.x + v.y * v.y + v.z * v.z + v.w * v.w;
  reduce2(s, ss);
  float mean = s * (1.f / HID);
  float var = ss * (1.f / HID) - mean * mean;
  float rstd = rsqrtf(var + 1e-5f);
  int c0 = tid * 4;
  float4 gv = ((const float4*)g)[tid];
  float4 bv = ((const float4*)b)[tid];
  bf16x4 o;
  o[0] = (bf16)((v.x - mean) * rstd * gv.x + bv.x);
  o[1] = (bf16)((v.y - mean) * rstd * gv.y + bv.y);
  o[2] = (bf16)((v.z - mean) * rstd * gv.z + bv.z);
  o[3] = (bf16)((v.w - mean) * rstd * gv.w + bv.w);
  if (c0 >= 256) {
    *(bf16x4*)(h + (size_t)t * HID + c0) = o;
  } else {
    if (t + 1 < SEQ) *(bf16x4*)(h + (size_t)(t + 1) * HID + c0) = o;
    if (t == 0) {
      bf16x4 z = {(bf16)0.f, (bf16)0.f, (bf16)0.f, (bf16)0.f};
      *(bf16x4*)(h + c0) = z;
    }
  }
}

// ---------------- q / k LN (bf16 in, bf16 out) ----------------
// q output is pre-scaled by 0.125*log2(e): attention softmax runs in log2
// domain with the 1/sqrt(64) scale folded in. k output unscaled.
__global__ __launch_bounds__(256) void ln_qk(const bf16* __restrict__ qkvp,
                                             const float* __restrict__ gq, const float* __restrict__ bq,
                                             const float* __restrict__ gk, const float* __restrict__ bk,
                                             bf16* __restrict__ qo, bf16* __restrict__ ko) {
  const int t = blockIdx.x, z = blockIdx.y, tid = threadIdx.x;
  const bf16* in = qkvp + (size_t)t * QKVPD + z * HID;
  bf16* out = (z ? ko : qo) + (size_t)t * HID;
  const float* g = z ? gk : gq;
  const float* bb = z ? bk : bq;
  const float osc = z ? 1.0f : 0.125f * L2E;
  int c0 = tid * 4;
  bf16x4 iv = *(const bf16x4*)(in + c0);
  float f0 = (float)iv[0], f1 = (float)iv[1], f2 = (float)iv[2], f3 = (float)iv[3];
  float s = f0 + f1 + f2 + f3;
  float ss = f0 * f0 + f1 * f1 + f2 * f2 + f3 * f3;
  reduce2(s, ss);
  float mean = s * (1.f / HID);
  float var = ss * (1.f / HID) - mean * mean;
  float rstd = rsqrtf(var + 1e-5f);
  float4 gv = ((const float4*)g)[tid];
  float4 bv = ((const float4*)bb)[tid];
  bf16x4 o;
  o[0] = (bf16)(((f0 - mean) * rstd * gv.x + bv.x) * osc);
  o[1] = (bf16)(((f1 - mean) * rstd * gv.y + bv.y) * osc);
  o[2] = (bf16)(((f2 - mean) * rstd * gv.z + bv.z) * osc);
  o[3] = (bf16)(((f3 - mean) * rstd * gv.w + bv.w) * osc);
  *(bf16x4*)(out + c0) = o;
}

// ---------------- mid LN (4096) + relu -> op[:, 1024:5120] ----------------
__global__ __launch_bounds__(256) void ln_mid(const bf16* __restrict__ qkvp,
                                              const float* __restrict__ g,
                                              const float* __restrict__ b,
                                              bf16* __restrict__ op) {
  const int t = blockIdx.x, tid = threadIdx.x;
  const bf16* in = qkvp + (size_t)t * QKVPD + 3 * HID;
  int c0 = tid * 16;
  bf16x8 a = *(const bf16x8*)(in + c0);
  bf16x8 a2 = *(const bf16x8*)(in + c0 + 8);
  float fv[16];
#pragma unroll
  for (int e = 0; e < 8; ++e) { fv[e] = (float)a[e]; fv[8 + e] = (float)a2[e]; }
  float s = 0.f, ss = 0.f;
#pragma unroll
  for (int e = 0; e < 16; ++e) { s += fv[e]; ss += fv[e] * fv[e]; }
  reduce2(s, ss);
  const float D = 4.f * HID;
  float mean = s / D;
  float var = ss / D - mean * mean;
  float rstd = rsqrtf(var + 1e-5f);
  bf16x8 o1, o2;
#pragma unroll
  for (int q = 0; q < 4; ++q) {
    float4 gv = ((const float4*)g)[tid * 4 + q];
    float4 bv = ((const float4*)b)[tid * 4 + q];
    float r0 = fmaxf(0.f, (fv[q * 4 + 0] - mean) * rstd * gv.x + bv.x);
    float r1 = fmaxf(0.f, (fv[q * 4 + 1] - mean) * rstd * gv.y + bv.y);
    float r2 = fmaxf(0.f, (fv[q * 4 + 2] - mean) * rstd * gv.z + bv.z);
    float r3 = fmaxf(0.f, (fv[q * 4 + 3] - mean) * rstd * gv.w + bv.w);
    if (q < 2) {
      o1[q * 4 + 0] = (bf16)r0; o1[q * 4 + 1] = (bf16)r1;
      o1[q * 4 + 2] = (bf16)r2; o1[q * 4 + 3] = (bf16)r3;
    } else {
      o2[(q - 2) * 4 + 0] = (bf16)r0; o2[(q - 2) * 4 + 1] = (bf16)r1;
      o2[(q - 2) * 4 + 2] = (bf16)r2; o2[(q - 2) * 4 + 3] = (bf16)r3;
    }
  }
  bf16* dst = op + (size_t)t * VPD + HID + c0;
  *(bf16x8*)dst = o1;
  *(bf16x8*)(dst + 8) = o2;
}

// ---------------- out LN: sum split-K partials + bias, then LN -> fp32 ----------------
__global__ __launch_bounds__(256) void ln_out(const float* __restrict__ cp0,
                                              const float* __restrict__ cp1,
                                              const float* __restrict__ bias,
                                              const float* __restrict__ g,
                                              const float* __restrict__ b,
                                              float* __restrict__ outp) {
  const int t = blockIdx.x, tid = threadIdx.x;
  float4 v  = ((const float4*)(cp0 + (size_t)t * HID))[tid];
  float4 v1 = ((const float4*)(cp1 + (size_t)t * HID))[tid];
  float4 bi = ((const float4*)bias)[tid];
  v.x += v1.x + bi.x; v.y += v1.y + bi.y; v.z += v1.z + bi.z; v.w += v1.w + bi.w;
  float s = v.x + v.y + v.z + v.w;
  float ss = v.x * v.x + v.y * v.y + v.z * v.z + v.w * v.w;
  reduce2(s, ss);
  float mean = s * (1.f / HID);
  float var = ss * (1.f / HID) - mean * mean;
  float rstd = rsqrtf(var + 1e-5f);
  float4 gv = ((const float4*)g)[tid];
  float4 bv = ((const float4*)b)[tid];
  float4 o;
  o.x = (v.x - mean) * rstd * gv.x + bv.x;
  o.y = (v.y - mean) * rstd * gv.y + bv.y;
  o.z = (v.z - mean) * rstd * gv.z + bv.z;
  o.w = (v.w - mean) * rstd * gv.w + bv.w;
  ((float4*)(outp + (size_t)t * HID))[tid] = o;
}

// ---------------- V transpose: qkvp[:, 2048+h*64+d] -> v_t[h][d][j] ----------------
__global__ __launch_bounds__(256) void vtrans(const bf16* __restrict__ qkvp,
                                              bf16* __restrict__ v_t) {
  const int h = blockIdx.y, j0 = blockIdx.x * 64, tid = threadIdx.x;
  __shared__ bf16 tile[64][72];
  int jr = tid >> 2, dcw = (tid & 3) * 16;
  const bf16* src = qkvp + (size_t)(j0 + jr) * QKVPD + 2 * HID + h * HD + dcw;
  bf16x8 a = *(const bf16x8*)src;
  bf16x8 a2 = *(const bf16x8*)(src + 8);
#pragma unroll
  for (int e = 0; e < 8; ++e) { tile[jr][dcw + e] = a[e]; tile[jr][dcw + 8 + e] = a2[e]; }
  __syncthreads();
  int d = tid >> 2, jc = (tid & 3) * 16;
  bf16x8 o1, o2;
#pragma unroll
  for (int e = 0; e < 8; ++e) { o1[e] = tile[jc + e][d]; o2[e] = tile[jc + 8 + e][d]; }
  bf16* dst = v_t + (size_t)(h * HD + d) * SEQ + j0 + jc;
  *(bf16x8*)dst = o1;
  *(bf16x8*)(dst + 8) = o2;
}

// ---------------- GEMM: C[M][N] = A[M][K]*B[N][K]^T, split-K via blockIdx.z ----
template <int OUT_BF16>
__global__ __launch_bounds__(256) void gemm_bt(const bf16* __restrict__ A,
                                               const bf16* __restrict__ B,
                                               void* __restrict__ Cout,
                                               int M, int N, int ld, int kLen,
                                               float scale) {
  __shared__ bf16 As[128 * 32], Bs[128 * 32];
  const int tid = threadIdx.x;
  const int l = tid & 63, w = tid >> 6;
  const int wr = w >> 1, wc = w & 1;
  const int lr = l & 15, lg = l >> 4;
  const int m0 = blockIdx.y * 128, n0 = blockIdx.x * 128;
  const int kBeg = blockIdx.z * kLen, kEnd = kBeg + kLen;

  f32x4 acc[4][4];
#pragma unroll
  for (int i = 0; i < 4; ++i)
#pragma unroll
    for (int j = 0; j < 4; ++j) acc[i][j] = (f32x4){0.f, 0.f, 0.f, 0.f};

  for (int k0 = kBeg; k0 < kEnd; k0 += 32) {
#pragma unroll
    for (int p = 0; p < 2; ++p) {
      int idx = p * 256 + tid;
      int row = idx >> 2, cc = (idx & 3) * 8;
      GLOAD_LDS16(A + (size_t)(m0 + row) * ld + k0 + cc, As + idx * 8);
      GLOAD_LDS16(B + (size_t)(n0 + row) * ld + k0 + cc, Bs + idx * 8);
    }
    __syncthreads();
    bf16x8 af[4], bfr[4];
#pragma unroll
    for (int i = 0; i < 4; ++i) {
      af[i]  = *(const bf16x8*)(As + (wr * 64 + i * 16 + lr) * 32 + lg * 8);
      bfr[i] = *(const bf16x8*)(Bs + (wc * 64 + i * 16 + lr) * 32 + lg * 8);
    }
#pragma unroll
    for (int i = 0; i < 4; ++i)
#pragma unroll
      for (int j = 0; j < 4; ++j) acc[i][j] = MFMA16(af[i], bfr[j], acc[i][j]);
    __syncthreads();
  }

  float* cf = (float*)Cout + (size_t)blockIdx.z * M * N;
#pragma unroll
  for (int i = 0; i < 4; ++i)
#pragma unroll
    for (int j = 0; j < 4; ++j)
#pragma unroll
      for (int r = 0; r < 4; ++r) {
        int rr = m0 + wr * 64 + i * 16 + lg * 4 + r;
        int cc = n0 + wc * 64 + j * 16 + lr;
        if (OUT_BF16)
          ((bf16*)Cout)[(size_t)rr * N + cc] = (bf16)acc[i][j][r];
        else
          cf[(size_t)rr * N + cc] = acc[i][j][r] * scale;
      }
}

// ---------------- causal flash attention, swapped QK^T ----------------
// grid = (NHEAD, 32); 256 threads = 4 independent waves, barrier-free.
// Wave role rotated by (w+y)&3 over {2y, 2y+1, 126-2y, 127-2y} so long and
// short causal waves mix across SIMDs. Each wave: 16 q rows, 64-col j-tiles.
// Swapped MFMA (a=K, b=Q) puts a full 64-col row-slice per lane-quad:
// row reduce = 15 in-reg ops + 2 shfl. Softmax in log2 domain (q pre-scaled
// by 0.125*log2e). acc_lg staged coalesced->LDS->transposed read.
__global__ __launch_bounds__(256) void attn_flash(const bf16* __restrict__ q_ln,
                                                  const bf16* __restrict__ k_ln,
                                                  const bf16* __restrict__ v_t,
                                                  const float* __restrict__ acc_lg,
                                                  bf16* __restrict__ o_out) {
  const int head = blockIdx.x;
  const int y = blockIdx.y;
  const int tid = threadIdx.x;
  const int w = tid >> 6, l = tid & 63;
  const int lr = l & 15, lg = l >> 4;
  const int role = (w + y) & 3;
  const int R = role == 0 ? 2 * y : role == 1 ? 2 * y + 1
              : role == 2 ? 126 - 2 * y : 127 - 2 * y;
  const int i0 = R * 16;
  const int hoff = head * HD;
  const float slope2 = exp2f(-0.5f * (float)(head + 1)) * L2E;  // alibi, log2 dom.

  __shared__ float bias_s[4][16][68];  // per-wave acc_lg tile (transposed read)
  __shared__ bf16 p_s[4][16][72];      // per-wave P[q][kj]
  float (*bw)[68] = bias_s[w];
  bf16 (*pw)[72] = p_s[w];

  bf16x8 qf[2];
#pragma unroll
  for (int kc = 0; kc < 2; ++kc)
    qf[kc] = *(const bf16x8*)(q_ln + (size_t)(i0 + lr) * HID + hoff + kc * 32 + lg * 8);

  f32x4 oacc[4] = {{0.f, 0.f, 0.f, 0.f}, {0.f, 0.f, 0.f, 0.f},
                   {0.f, 0.f, 0.f, 0.f}, {0.f, 0.f, 0.f, 0.f}};
  float mrow = -3e38f, lsum = 0.f;
  const int iq = i0 + lr;   // this lane's q row index

  for (int j0 = 0; j0 <= i0 + 15; j0 += 64) {
    // ---- issue all global loads up front (K, V, acc_lg block) ----
    bf16x8 kf[4][2];
#pragma unroll
    for (int t = 0; t < 4; ++t)
#pragma unroll
      for (int kc = 0; kc < 2; ++kc)
        kf[t][kc] = *(const bf16x8*)(k_ln + (size_t)(j0 + t * 16 + lr) * HID +
                                     hoff + kc * 32 + lg * 8);
    bf16x8 vv[4][2];
#pragma unroll
    for (int dt = 0; dt < 4; ++dt)
#pragma unroll
      for (int c = 0; c < 2; ++c)
        vv[dt][c] = *(const bf16x8*)(v_t + (size_t)(hoff + dt * 16 + lr) * SEQ +
                                     j0 + c * 32 + lg * 8);
    float4 bld[4];
    {
      const float* bp = acc_lg + (size_t)(i0 + (l >> 2)) * SEQ + j0 + (l & 3) * 4;
#pragma unroll
      for (int qx = 0; qx < 4; ++qx) bld[qx] = *(const float4*)(bp + qx * 16);
    }
    // ---- QK^T swapped: st[t] holds S^T[kj = 16t+4lg+r][q = lr] ----
    f32x4 st[4];
#pragma unroll
    for (int t = 0; t < 4; ++t) {
      f32x4 a = {0.f, 0.f, 0.f, 0.f};
      a = MFMA16(kf[t][0], qf[0], a);
      a = MFMA16(kf[t][1], qf[1], a);
      st[t] = a;
    }
    // ---- stage acc_lg block to LDS (coalesced write, transposed read) ----
#pragma unroll
    for (int qx = 0; qx < 4; ++qx)
      *(float4*)&bw[l >> 2][(l & 3) * 4 + qx * 16] = bld[qx];
    asm volatile("s_waitcnt lgkmcnt(0)" ::: "memory");
    __builtin_amdgcn_sched_barrier(0);
    // ---- logits (log2 domain): f = s' + acc*log2e + slope2*j (+mask) ----
    const bool diag = (j0 + 64 > i0);
#pragma unroll
    for (int t = 0; t < 4; ++t) {
      f32x4 b4 = *(const f32x4*)&bw[lr][t * 16 + lg * 4];
      float jt = (float)(j0 + t * 16 + lg * 4);
#pragma unroll
      for (int r = 0; r < 4; ++r) {
        float f = fmaf(b4[r], L2E, st[t][r]);
        f = fmaf(slope2, jt + (float)r, f);
        if (diag) {
          int j = j0 + t * 16 + lg * 4 + r;
          f = (j <= iq) ? f : -1e30f;
        }
        st[t][r] = f;
      }
    }
    // ---- online softmax: one reduce per 64 cols (in-reg + 2 shfl) ----
    float pm = st[0][0];
#pragma unroll
    for (int t = 0; t < 4; ++t)
#pragma unroll
      for (int r = 0; r < 4; ++r) pm = fmaxf(pm, st[t][r]);
    pm = fmaxf(pm, __shfl_xor(pm, 16));
    pm = fmaxf(pm, __shfl_xor(pm, 32));
    float mnew = fmaxf(mrow, pm);
    float scl = exp2f(mrow - mnew);
    float ps = 0.f;
#pragma unroll
    for (int t = 0; t < 4; ++t)
#pragma unroll
      for (int r = 0; r < 4; ++r) {
        float p = exp2f(st[t][r] - mnew);
        st[t][r] = p;
        ps += p;
      }
    ps += __shfl_xor(ps, 16);
    ps += __shfl_xor(ps, 32);
    lsum = lsum * scl + ps;
    mrow = mnew;
#pragma unroll
    for (int dt = 0; dt < 4; ++dt) oacc[dt] *= scl;
    // ---- P -> LDS in B-fragment layout [q][kj] ----
#pragma unroll
    for (int t = 0; t < 4; ++t) {
      bf16x4 pk = {(bf16)st[t][0], (bf16)st[t][1], (bf16)st[t][2], (bf16)st[t][3]};
      *(bf16x4*)&pw[lr][t * 16 + lg * 4] = pk;
    }
    asm volatile("s_waitcnt lgkmcnt(0)" ::: "memory");
    __builtin_amdgcn_sched_barrier(0);
    // ---- PV: O^T[d][q] += V^T[d][kj] * P^T[kj][q] ----
    bf16x8 pf[2];
#pragma unroll
    for (int c = 0; c < 2; ++c)
      pf[c] = *(const bf16x8*)&pw[lr][c * 32 + lg * 8];
#pragma unroll
    for (int dt = 0; dt < 4; ++dt)
#pragma unroll
      for (int c = 0; c < 2; ++c)
        oacc[dt] = MFMA16(vv[dt][c], pf[c], oacc[dt]);
  }

  const float rl = 1.f / lsum;
#pragma unroll
  for (int dt = 0; dt < 4; ++dt) {
    bf16x4 ov = {(bf16)(oacc[dt][0] * rl), (bf16)(oacc[dt][1] * rl),
                 (bf16)(oacc[dt][2] * rl), (bf16)(oacc[dt][3] * rl)};
    *(bf16x4*)(o_out + (size_t)(i0 + lr) * VPD + hoff + dt * 16 + lg * 4) = ov;
  }
}

// ---------------- launch ----------------
extern "C" void kernel_launch(void* const* d_in, const int* in_sizes, int n_in,
                              void* d_out, int out_size, void* d_ws, size_t ws_size,
                              hipStream_t stream) {
  const float* x      = (const float*)d_in[0];
  const float* acc_lg = (const float*)d_in[1];
  const float* w_in   = (const float*)d_in[2];
  const float* w_out  = (const float*)d_in[3];
  const float* b_out  = (const float*)d_in[4];
  const float* g_in   = (const float*)d_in[5];
  const float* bi_in  = (const float*)d_in[6];
  const float* g_q    = (const float*)d_in[7];
  const float* bi_q   = (const float*)d_in[8];
  const float* g_k    = (const float*)d_in[9];
  const float* bi_k   = (const float*)d_in[10];
  const float* g_mid  = (const float*)d_in[11];
  const float* bi_mid = (const float*)d_in[12];
  const float* g_out  = (const float*)d_in[13];
  const float* bi_o   = (const float*)d_in[14];

  char* ws = (char*)d_ws;
  bf16* h_shift = (bf16*)(ws + 0);            //  4 MB  [2048][1024]
  bf16* wA      = (bf16*)(ws + 4194304);      // 14 MB  [7168][1024]
  bf16* wO      = (bf16*)(ws + 18874368);     // 10 MB  [1024][5120]
  bf16* qkvp    = (bf16*)(ws + 29360128);     // 29 MB  [2048][7168]
  bf16* q_ln    = (bf16*)(ws + 58720256);     //  4 MB  (pre-scaled by 0.125*log2e)
  bf16* k_ln    = (bf16*)(ws + 62914560);     //  4 MB
  bf16* v_t     = (bf16*)(ws + 67108864);     //  4 MB  [16][64][2048]
  bf16* op      = (bf16*)(ws + 71303168);     // 21 MB  [2048][5120] (o | p)
  // out_pre (2 split-K partials, 16 MB fp32) aliases qkvp: all qkvp consumers
  // (ln_qk, ln_mid, vtrans) run before gemm2 writes it.
  float* out_pre = (float*)qkvp;

  float* outp  = (float*)d_out;
  float* resid = outp + (size_t)SEQ * HID;

  cvt_f32_bf16<<<7168, 256, 0, stream>>>(w_in, wA, QKVPD * HID / 4);
  cvt_f32_bf16<<<5120, 256, 0, stream>>>(w_out, wO, HID * VPD / 4);
  ln_in_shift<<<SEQ, 256, 0, stream>>>(x, g_in, bi_in, h_shift);
  gemm_bt<1><<<dim3(QKVPD / 128, SEQ / 128), 256, 0, stream>>>(
      h_shift, wA, qkvp, SEQ, QKVPD, HID, HID, 1.f);
  ln_qk<<<dim3(SEQ, 2), 256, 0, stream>>>(qkvp, g_q, bi_q, g_k, bi_k, q_ln, k_ln);
  ln_mid<<<SEQ, 256, 0, stream>>>(qkvp, g_mid, bi_mid, op);
  vtrans<<<dim3(SEQ / 64, NHEAD), 256, 0, stream>>>(qkvp, v_t);
  // logit_residual = (q.k)/128; q pre-scaled by 0.125*log2e -> scale 1/(16*log2e)
  gemm_bt<0><<<dim3(SEQ / 128, SEQ / 128), 256, 0, stream>>>(
      q_ln, k_ln, resid, SEQ, SEQ, HID, HID, 1.f / (16.f * L2E));
  attn_flash<<<dim3(NHEAD, 32), 256, 0, stream>>>(q_ln, k_ln, v_t, acc_lg, op);
  gemm_bt<0><<<dim3(HID / 128, SEQ / 128, 2), 256, 0, stream>>>(
      op, wO, out_pre, SEQ, HID, VPD, VPD / 2, 1.f);
  ln_out<<<SEQ, 256, 0, stream>>>(out_pre, out_pre + (size_t)SEQ * HID,
                                  b_out, g_out, bi_o, outp);
}